// Round 3
// baseline (902.178 us; speedup 1.0000x reference)
//
#include <hip/hip_runtime.h>

// Infusion: local dilated-window attention, float32 end-to-end.
// N=8, C=256 (8 heads x 32 ch), H=W=128, ksize=5, dilation=3, pad=6, 25 taps.
//
// V4: V3's double-buffered 2-channel-period pipeline, with the LDS inner loop
// rebuilt around aligned ds_read_b128 + immediate offsets:
//  - Reads: per row, 5 aligned float4 covering cols [xs, xs+19] (window
//    cols xs+2..xs+17 used; 2 pad words each side). Lane stride 16B b128 is
//    conflict-free (each 32-lane phase hits all 32 banks at the 4-access
//    data-path floor). V3's b64-at-16B-stride was a 4-way conflict WITHIN a
//    half-wave (same row, 8 start banks) -> 4.7e7 conflict cycles (~38% wall).
//  - LSTR = 144 (0 mod 4) so rows/quads stay 16B-aligned; staging writes are
//    ds_write_b128 (consecutive lanes -> consecutive 16B, floor).
//  - All LDS addressing folded to compile-time immediates: period bodies are
//    template<int BI> instantiations, so buffer/channel/fy/j offsets are
//    literals (max 41536 B < 64K ds imm). One base VGPR, ~0 address VALU.
//  - Same zero-padded-border trick: borders + OOB rows zeroed once, never
//    rewritten -> padding semantics with zero masking in the loop.

#define Hh 128
#define Ww 128
#define HD 32
#define TAPS 25
#define LROWS 20
#define LSTR 144           // floats; col = x + 8; interior cols 8..135
#define CHW (LROWS * LSTR) // 2880 floats per channel tile
#define BUFW (2 * CHW)     // 5760 floats per 2-channel buffer

typedef float4 f4;

template<int NBI>
__device__ __forceinline__ void write_group(float* const (&wp)[3], const bool (&sgv)[3],
                                            const f4 (&stg)[6]) {
#pragma unroll
    for (int cc = 0; cc < 2; ++cc)
#pragma unroll
        for (int k = 0; k < 3; ++k)
            if (sgv[k])
                *(f4*)(wp[k] + NBI * BUFW + cc * CHW) = stg[cc * 3 + k];
}

template<int BI>
__device__ __forceinline__ void score_period(const float* lbase, const f4 q0, const f4 q1,
                                             float (&s)[4][TAPS]) {
#pragma unroll
    for (int cc = 0; cc < 2; ++cc) {
        const f4 q = cc ? q1 : q0;
#pragma unroll
        for (int fy = 0; fy < 5; ++fy) {
            const float* rp = lbase + BI * BUFW + cc * CHW + fy * (3 * LSTR);
            const f4 w0 = *(const f4*)(rp + 0);
            const f4 w1 = *(const f4*)(rp + 4);
            const f4 w2 = *(const f4*)(rp + 8);
            const f4 w3 = *(const f4*)(rp + 12);
            const f4 w4 = *(const f4*)(rp + 16);
            const float v[20] = { w0.x, w0.y, w0.z, w0.w,  w1.x, w1.y, w1.z, w1.w,
                                  w2.x, w2.y, w2.z, w2.w,  w3.x, w3.y, w3.z, w3.w,
                                  w4.x, w4.y, w4.z, w4.w };
#pragma unroll
            for (int fx = 0; fx < 5; ++fx) {
                const int p = fy * 5 + fx;
                s[0][p] = fmaf(v[2 + 3 * fx], q.x, s[0][p]);
                s[1][p] = fmaf(v[3 + 3 * fx], q.y, s[1][p]);
                s[2][p] = fmaf(v[4 + 3 * fx], q.z, s[2][p]);
                s[3][p] = fmaf(v[5 + 3 * fx], q.w, s[3][p]);
            }
        }
    }
}

template<int BI>
__device__ __forceinline__ void pv_period(const float* lbase, const float (&s)[4][TAPS],
                                          float* op, const size_t plane) {
#pragma unroll
    for (int cc = 0; cc < 2; ++cc) {
        float a0 = 0.f, a1 = 0.f, a2 = 0.f, a3 = 0.f;
#pragma unroll
        for (int fy = 0; fy < 5; ++fy) {
            const float* rp = lbase + BI * BUFW + cc * CHW + fy * (3 * LSTR);
            const f4 w0 = *(const f4*)(rp + 0);
            const f4 w1 = *(const f4*)(rp + 4);
            const f4 w2 = *(const f4*)(rp + 8);
            const f4 w3 = *(const f4*)(rp + 12);
            const f4 w4 = *(const f4*)(rp + 16);
            const float v[20] = { w0.x, w0.y, w0.z, w0.w,  w1.x, w1.y, w1.z, w1.w,
                                  w2.x, w2.y, w2.z, w2.w,  w3.x, w3.y, w3.z, w3.w,
                                  w4.x, w4.y, w4.z, w4.w };
#pragma unroll
            for (int fx = 0; fx < 5; ++fx) {
                const int p = fy * 5 + fx;
                a0 = fmaf(v[2 + 3 * fx], s[0][p], a0);
                a1 = fmaf(v[3 + 3 * fx], s[1][p], a1);
                a2 = fmaf(v[4 + 3 * fx], s[2][p], a2);
                a3 = fmaf(v[5 + 3 * fx], s[3][p], a3);
            }
        }
        *(f4*)(op + cc * plane) = make_float4(a0, a1, a2, a3);
    }
}

__global__ __launch_bounds__(256, 2) void infusion_kernel(
    const float* __restrict__ Vt,
    const float* __restrict__ Kt,
    const float* __restrict__ Qt,
    float* __restrict__ Ot)
{
    __shared__ alignas(16) float lbuf[2][BUFW];  // 46080 B

    const int tid = threadIdx.x;
    const int tx  = tid & 31;   // x-group (4 pixels each)
    const int ty  = tid >> 5;   // 0..7
    const int Rb  = blockIdx.x * 8;
    const int row = Rb + ty;
    const int nh  = blockIdx.y; // n*8 + head
    const int xs  = tx << 2;

    const size_t plane = (size_t)Hh * Ww;
    const size_t cbase = (size_t)nh * HD * plane;
    const int qoff = row * Ww + xs;

    // staging map: 640 chunks of 16B (20 rows x 32 xchunks) per channel.
    bool sgv[3]; int sgo[3]; float* wp[3];
#pragma unroll
    for (int k = 0; k < 3; ++k) {
        const int q  = tid + (k << 8);
        const int lr = q >> 5, xc = q & 31;
        const int r  = Rb + lr - 6;
        const bool ok = (q < 640) && (r >= 0) && (r < Hh);
        sgv[k] = ok;
        sgo[k] = ok ? (r * Ww + (xc << 2)) : 0;
        wp[k]  = &lbuf[0][0] + (lr < LROWS ? lr : 0) * LSTR + 8 + (xc << 2);
    }

    // zero both buffers once; borders and OOB rows stay zero forever
    for (int i = tid; i < 2 * BUFW; i += 256) (&lbuf[0][0])[i] = 0.f;

    const float* Kb = Kt + cbase;
    const float* Qb = Qt + cbase;
    const float* Vb = Vt + cbase;
    float*       Ob = Ot + cbase;
    const float* lbase = &lbuf[0][0] + ty * LSTR + xs;

    f4 stg[6];
    auto loadg = [&](const float* B, int g) {  // issue group = channels g, g+1
        const float* p0 = B + (size_t)g * plane;
        const float* p1 = p0 + plane;
        stg[0] = *(const f4*)(p0 + sgo[0]);
        stg[1] = *(const f4*)(p0 + sgo[1]);
        stg[2] = *(const f4*)(p0 + sgo[2]);
        stg[3] = *(const f4*)(p1 + sgo[0]);
        stg[4] = *(const f4*)(p1 + sgo[1]);
        stg[5] = *(const f4*)(p1 + sgo[2]);
    };

    float s[4][TAPS];
#pragma unroll
    for (int a = 0; a < 4; ++a)
#pragma unroll
        for (int p = 0; p < TAPS; ++p) s[a][p] = 0.f;

    // ---------------- phase 1: scores = K . Q over 32 channels ----------------
    {
        loadg(Kb, 0);
        f4 qc0 = *(const f4*)(Qb + qoff);
        f4 qc1 = *(const f4*)(Qb + plane + qoff);
        f4 qn0 = qc0, qn1 = qc1;
        __syncthreads();            // zero-init visible (drains group-0 loads)
        write_group<0>(wp, sgv, stg);
        loadg(Kb, 2);
        __syncthreads();            // buf0 visible
#pragma unroll 1
        for (int itp = 0; itp < 8; ++itp) {
            const int it0 = 2 * itp;
            // -- even period: compute buf0 (group it0), write buf1 (group it0+1)
            write_group<1>(wp, sgv, stg);
            if (it0 < 14) loadg(Kb, 2 * it0 + 4);
            qn0 = *(const f4*)(Qb + (size_t)(2 * it0 + 2) * plane + qoff);
            qn1 = *(const f4*)(Qb + (size_t)(2 * it0 + 3) * plane + qoff);
            score_period<0>(lbase, qc0, qc1, s);
            __syncthreads();        // drains this period's prefetch
            qc0 = qn0; qc1 = qn1;
            // -- odd period: compute buf1 (group it0+1), write buf0 (group it0+2)
            const int it1 = it0 + 1;
            if (it1 < 15) write_group<0>(wp, sgv, stg);
            if (it1 < 14) loadg(Kb, 2 * it1 + 4);
            if (it1 < 15) {
                qn0 = *(const f4*)(Qb + (size_t)(2 * it1 + 2) * plane + qoff);
                qn1 = *(const f4*)(Qb + (size_t)(2 * it1 + 3) * plane + qoff);
            }
            score_period<1>(lbase, qc0, qc1, s);
            __syncthreads();
            qc0 = qn0; qc1 = qn1;
        }
    }

    // ---------------- phase 2 prologue: V group 0 in flight under softmax ----
    loadg(Vb, 0);

    // ---------------- softmax over the 25 taps ----------------
#pragma unroll
    for (int a = 0; a < 4; ++a) {
        float m = s[a][0];
#pragma unroll
        for (int p = 1; p < TAPS; ++p) m = fmaxf(m, s[a][p]);
        float sum = 0.f;
#pragma unroll
        for (int p = 0; p < TAPS; ++p) { float e = __expf(s[a][p] - m); s[a][p] = e; sum += e; }
        const float rs = 1.0f / sum;
#pragma unroll
        for (int p = 0; p < TAPS; ++p) s[a][p] *= rs;
    }

    // ---------------- phase 2: out = sum_p att[p] * V_shift[p] ----------------
    {
        write_group<0>(wp, sgv, stg);   // waits on the softmax-covered loads
        loadg(Vb, 2);
        __syncthreads();
        float* op = Ob + qoff;
#pragma unroll 1
        for (int itp = 0; itp < 8; ++itp) {
            const int it0 = 2 * itp;
            write_group<1>(wp, sgv, stg);
            if (it0 < 14) loadg(Vb, 2 * it0 + 4);
            pv_period<0>(lbase, s, op, plane);
            op += 2 * plane;
            __syncthreads();
            const int it1 = it0 + 1;
            if (it1 < 15) write_group<0>(wp, sgv, stg);
            if (it1 < 14) loadg(Vb, 2 * it1 + 4);
            pv_period<1>(lbase, s, op, plane);
            op += 2 * plane;
            __syncthreads();
        }
    }
}

extern "C" void kernel_launch(void* const* d_in, const int* in_sizes, int n_in,
                              void* d_out, int out_size, void* d_ws, size_t ws_size,
                              hipStream_t stream) {
    const float* V = (const float*)d_in[0];
    const float* K = (const float*)d_in[1];
    const float* Q = (const float*)d_in[2];
    // d_in[3] = ksize (5), d_in[4] = dilation (3): fixed by setup_inputs.
    float* O = (float*)d_out;

    const int N = in_sizes[0] / (256 * Hh * Ww);  // = 8
    dim3 grid(Hh / 8, N * 8);
    dim3 block(256);
    infusion_kernel<<<grid, block, 0, stream>>>(V, K, Q, O);
}